// Round 5
// baseline (558.787 us; speedup 1.0000x reference)
//
#include <hip/hip_runtime.h>
#include <cmath>

#define TS 2048   // sequence
#define TH 768    // hidden
#define TNH 12    // heads
#define THD 64    // head dim
#define TNF 128   // rff features
#define KC 192    // concat K for scores (64 dot + 128 rff)

typedef __attribute__((ext_vector_type(4))) short s16x4;     // NOTE: 'short4' collides with HIP's vector types
typedef __attribute__((ext_vector_type(8))) short short8;
typedef __attribute__((ext_vector_type(8))) __bf16 bf16x8;   // matches builtin signature V8y
typedef __attribute__((ext_vector_type(4))) float floatx4;

// ---------------- fp32 <-> bf16 helpers ----------------
__device__ __forceinline__ short f2bf(float x) {
    union { float f; unsigned u; } v; v.f = x;
    unsigned r = v.u + 0x7FFFu + ((v.u >> 16) & 1u);   // round-nearest-even
    return (short)(r >> 16);
}
__device__ __forceinline__ float bf2f(short x) {
    union { unsigned u; float f; } v;
    v.u = ((unsigned)(unsigned short)x) << 16;
    return v.f;
}

// ---------------- wave helpers (wave = 64) ----------------
__device__ __forceinline__ float waveReduceSum(float v) {
#pragma unroll
    for (int off = 32; off >= 1; off >>= 1) v += __shfl_xor(v, off, 64);
    return v;
}

// ---------------- cvt: fp32 -> bf16 for hs, Wq, Wk, Wv, Wo, omega ----------------
__global__ __launch_bounds__(256) void k_cvt_bf16(
    const float* __restrict__ s0, const float* __restrict__ s1,
    const float* __restrict__ s2, const float* __restrict__ s3,
    const float* __restrict__ s4, const float* __restrict__ s5,
    short* __restrict__ d0, short* __restrict__ d1,
    short* __restrict__ d2, short* __restrict__ d3,
    short* __restrict__ d4, short* __restrict__ d5) {
    const int y = blockIdx.y;
    const float* srcs[6] = {s0, s1, s2, s3, s4, s5};
    short* dsts[6] = {d0, d1, d2, d3, d4, d5};
    const int n4s[6] = {TS * TH / 4, TH * TH / 4, TH * TH / 4, TH * TH / 4,
                        TH * TH / 4, TNH * TNF * THD / 4};
    const float* src = srcs[y];
    short* dst = dsts[y];
    const int n4 = n4s[y];
    for (int i = blockIdx.x * 256 + threadIdx.x; i < n4; i += gridDim.x * 256) {
        float4 v = ((const float4*)src)[i];
        s16x4 o;
        o[0] = f2bf(v.x); o[1] = f2bf(v.y); o[2] = f2bf(v.z); o[3] = f2bf(v.w);
        *(s16x4*)&dst[i * 4] = o;
    }
}

// ---------------- QKV projection (bf16 MFMA): Y = X @ W^T + b, scatter to (h,s,d) ----------------
__global__ __launch_bounds__(256) void k_proj_qkv_mfma(
    const short* __restrict__ Xb,
    const short* __restrict__ Wqb, const short* __restrict__ Wkb, const short* __restrict__ Wvb,
    const float* __restrict__ b0, const float* __restrict__ b1, const float* __restrict__ b2,
    float* __restrict__ dq, float* __restrict__ dk, short* __restrict__ Vb,
    short* __restrict__ Qc, short* __restrict__ Kc) {
    __shared__ __align__(16) short Asb[128][40];
    __shared__ __align__(16) short Bsb[128][40];
    const int z = blockIdx.z;
    const short* W = (z == 0) ? Wqb : ((z == 1) ? Wkb : Wvb);
    const float* bias = (z == 0) ? b0 : ((z == 1) ? b1 : b2);
    const int n0 = blockIdx.x * 128;
    const int m0 = blockIdx.y * 128;
    const int tid = threadIdx.x;
    const int lane = tid & 63;
    const int w = tid >> 6;
    const int wm = (w >> 1) * 64, wn = (w & 1) * 64;
    const int fr = lane & 15;
    const int quad = lane >> 4;

    floatx4 acc[4][4] = {};

    for (int k0 = 0; k0 < TH; k0 += 32) {
#pragma unroll
        for (int l = 0; l < 2; ++l) {
            int c = tid + l * 256;
            int row = c >> 2, col = (c & 3) << 3;
            *(short8*)&Asb[row][col] = *(const short8*)&Xb[(size_t)(m0 + row) * TH + k0 + col];
            *(short8*)&Bsb[row][col] = *(const short8*)&W[(size_t)(n0 + row) * TH + k0 + col];
        }
        __syncthreads();
        bf16x8 af[4], bfr[4];
#pragma unroll
        for (int i = 0; i < 4; ++i) af[i] = *(const bf16x8*)&Asb[wm + i * 16 + fr][quad * 8];
#pragma unroll
        for (int j = 0; j < 4; ++j) bfr[j] = *(const bf16x8*)&Bsb[wn + j * 16 + fr][quad * 8];
#pragma unroll
        for (int i = 0; i < 4; ++i)
#pragma unroll
            for (int j = 0; j < 4; ++j)
                acc[i][j] = __builtin_amdgcn_mfma_f32_16x16x32_bf16(af[i], bfr[j], acc[i][j], 0, 0, 0);
        __syncthreads();
    }
    // epilogue: C/D layout col=lane&15, row=(lane>>4)*4+reg
    if (z == 2) {
#pragma unroll
        for (int j = 0; j < 4; ++j) {
            int n = n0 + wn + j * 16 + fr;
            int h = n >> 6, d = n & 63;
            float bv = bias[n];
#pragma unroll
            for (int i = 0; i < 4; ++i) {
                int t = m0 + wm + i * 16 + quad * 4;
                s16x4 pk;
#pragma unroll
                for (int r = 0; r < 4; ++r) pk[r] = f2bf(acc[i][j][r] + bv);
                *(s16x4*)&Vb[(size_t)(h * THD + d) * TS + t] = pk;
            }
        }
    } else {
        float* dst = z ? dk : dq;
        short* cc = z ? Kc : Qc;
        const float qs = z ? 1.0f : 0.1125f;
#pragma unroll
        for (int j = 0; j < 4; ++j) {
            int n = n0 + wn + j * 16 + fr;
            int h = n >> 6, d = n & 63;
            float bv = bias[n];
#pragma unroll
            for (int i = 0; i < 4; ++i) {
#pragma unroll
                for (int r = 0; r < 4; ++r) {
                    int m = m0 + wm + i * 16 + quad * 4 + r;
                    float val = acc[i][j][r] + bv;
                    size_t rowi = (size_t)(h * TS + m);
                    dst[rowi * THD + d] = val;
                    cc[rowi * KC + d] = f2bf(val * qs);
                }
            }
        }
    }
}

// ---------------- output projection (bf16 MFMA): out = ctxb @ Wob^T + bo ----------------
__global__ __launch_bounds__(256) void k_proj_out_mfma(
    const short* __restrict__ ctxb, const short* __restrict__ Wob,
    const float* __restrict__ bias, float* __restrict__ out) {
    __shared__ __align__(16) short Asb[128][40];
    __shared__ __align__(16) short Bsb[128][40];
    const int n0 = blockIdx.x * 128;
    const int m0 = blockIdx.y * 128;
    const int tid = threadIdx.x;
    const int lane = tid & 63;
    const int w = tid >> 6;
    const int wm = (w >> 1) * 64, wn = (w & 1) * 64;
    const int fr = lane & 15;
    const int quad = lane >> 4;

    floatx4 acc[4][4] = {};

    for (int k0 = 0; k0 < TH; k0 += 32) {
#pragma unroll
        for (int l = 0; l < 2; ++l) {
            int c = tid + l * 256;
            int row = c >> 2, col = (c & 3) << 3;
            *(short8*)&Asb[row][col] = *(const short8*)&ctxb[(size_t)(m0 + row) * TH + k0 + col];
            *(short8*)&Bsb[row][col] = *(const short8*)&Wob[(size_t)(n0 + row) * TH + k0 + col];
        }
        __syncthreads();
        bf16x8 af[4], bfr[4];
#pragma unroll
        for (int i = 0; i < 4; ++i) af[i] = *(const bf16x8*)&Asb[wm + i * 16 + fr][quad * 8];
#pragma unroll
        for (int j = 0; j < 4; ++j) bfr[j] = *(const bf16x8*)&Bsb[wn + j * 16 + fr][quad * 8];
#pragma unroll
        for (int i = 0; i < 4; ++i)
#pragma unroll
            for (int j = 0; j < 4; ++j)
                acc[i][j] = __builtin_amdgcn_mfma_f32_16x16x32_bf16(af[i], bfr[j], acc[i][j], 0, 0, 0);
        __syncthreads();
    }
#pragma unroll
    for (int j = 0; j < 4; ++j) {
        int n = n0 + wn + j * 16 + fr;
        float bv = bias[n];
#pragma unroll
        for (int i = 0; i < 4; ++i)
#pragma unroll
            for (int r = 0; r < 4; ++r) {
                int m = m0 + wm + i * 16 + quad * 4 + r;
                out[(size_t)m * TH + n] = acc[i][j][r] + bv;
            }
    }
}

// ---------------- row inverse norms for q,k ----------------
__global__ __launch_bounds__(64) void k_rownorm(
    const float* __restrict__ q, const float* __restrict__ kbuf,
    float* __restrict__ invq, float* __restrict__ invk) {
    const int row = blockIdx.x;
    const float* src = blockIdx.y ? kbuf : q;
    float* dst = blockIdx.y ? invk : invq;
    float x = src[row * THD + threadIdx.x];
    float ss = waveReduceSum(x * x);
    if (threadIdx.x == 0) dst[row] = 1.0f / (sqrtf(ss) + 1e-5f);
}

// ---------------- phi (bf16 MFMA): Z = (x*inv) @ omega[h]^T ; write bf16(0.125*cos(Z+b)) ----------------
__global__ __launch_bounds__(256) void k_phi_mfma(
    const float* __restrict__ q, const float* __restrict__ kbuf,
    const float* __restrict__ invq, const float* __restrict__ invk,
    const short* __restrict__ omegab, const float* __restrict__ rffb,
    short* __restrict__ Qc, short* __restrict__ Kc) {
    __shared__ __align__(16) short Asb[128][40];
    __shared__ __align__(16) short Bsb[128][40];
    const int z = blockIdx.y;
    const int h = z >> 1, which = z & 1;
    const float* X = which ? kbuf : q;
    const float* inv = which ? invk : invq;
    short* dst = which ? Kc : Qc;
    const int m0 = blockIdx.x * 128;
    const int tid = threadIdx.x;
    const int lane = tid & 63;
    const int w = tid >> 6;
    const int wm = (w >> 1) * 64, wn = (w & 1) * 64;
    const int fr = lane & 15;
    const int quad = lane >> 4;

    floatx4 acc[4][4] = {};

    for (int k0 = 0; k0 < THD; k0 += 32) {
#pragma unroll
        for (int l = 0; l < 2; ++l) {
            int c = tid + l * 256;
            int row = c >> 2, col = (c & 3) << 3;
            int rq = h * TS + m0 + row;
            float s = inv[rq];
            float4 a0 = *(const float4*)&X[(size_t)rq * THD + k0 + col];
            float4 a1 = *(const float4*)&X[(size_t)rq * THD + k0 + col + 4];
            short8 o;
            o[0] = f2bf(a0.x * s); o[1] = f2bf(a0.y * s);
            o[2] = f2bf(a0.z * s); o[3] = f2bf(a0.w * s);
            o[4] = f2bf(a1.x * s); o[5] = f2bf(a1.y * s);
            o[6] = f2bf(a1.z * s); o[7] = f2bf(a1.w * s);
            *(short8*)&Asb[row][col] = o;
            *(short8*)&Bsb[row][col] = *(const short8*)&omegab[(size_t)(h * TNF + row) * THD + k0 + col];
        }
        __syncthreads();
        bf16x8 af[4], bfr[4];
#pragma unroll
        for (int i = 0; i < 4; ++i) af[i] = *(const bf16x8*)&Asb[wm + i * 16 + fr][quad * 8];
#pragma unroll
        for (int j = 0; j < 4; ++j) bfr[j] = *(const bf16x8*)&Bsb[wn + j * 16 + fr][quad * 8];
#pragma unroll
        for (int i = 0; i < 4; ++i)
#pragma unroll
            for (int j = 0; j < 4; ++j)
                acc[i][j] = __builtin_amdgcn_mfma_f32_16x16x32_bf16(af[i], bfr[j], acc[i][j], 0, 0, 0);
        __syncthreads();
    }
#pragma unroll
    for (int j = 0; j < 4; ++j) {
        int f = wn + j * 16 + fr;
        float bv = rffb[h * TNF + f];
#pragma unroll
        for (int i = 0; i < 4; ++i)
#pragma unroll
            for (int r = 0; r < 4; ++r) {
                int m = m0 + wm + i * 16 + quad * 4 + r;
                float zv = acc[i][j][r] + bv;   // SIGMA = 1
                dst[(size_t)(h * TS + m) * KC + 64 + f] = f2bf(0.125f * cosf(zv));
            }
    }
}

// ---------------- phi row L2-normalize in place (bf16); fold (1-alpha)=0.1 into phi_q ----------------
__global__ __launch_bounds__(128) void k_phinorm(short* __restrict__ Qc, short* __restrict__ Kc) {
    const int row = blockIdx.x;
    short* buf = (blockIdx.y ? Kc : Qc) + (size_t)row * KC + 64;
    const float scale0 = blockIdx.y ? 1.0f : 0.1f;
    const int tid = threadIdx.x;
    float p = bf2f(buf[tid]);
    float ss = waveReduceSum(p * p);
    __shared__ float sh[2];
    if ((tid & 63) == 0) sh[tid >> 6] = ss;
    __syncthreads();
    ss = sh[0] + sh[1];
    float sc = scale0 / (sqrtf(ss) + 1e-6f);
    buf[tid] = f2bf(p * sc);
}

// ---------------- fused scores + softmax: 16-row strip per block, scores live in registers ----------------
// Block = 4 waves, head h, rows [m0, m0+16). Wave w owns cols {c*128 + w*32 + sub*16 + fr}.
// QK^T (K=192 concat) -> +mask -> row softmax (in-lane 32-max -> shfl over fr -> LDS over waves)
// -> write fp32 weights to wout ONCE. Eliminates the scores write + softmax read/write (402 MB).
__global__ __launch_bounds__(256) void k_qk_sm(
    const short* __restrict__ Qc, const short* __restrict__ Kc,
    const float* __restrict__ mask, float* __restrict__ wout) {
    __shared__ __align__(16) short Qs[16][200];    // 200-short stride: 400B -> 2-way bank alias max
    __shared__ __align__(16) short Ks[128][200];
    __shared__ float smM[4][16];
    __shared__ float smS[4][16];
    const int h = blockIdx.y;
    const int m0 = blockIdx.x * 16;
    const int tid = threadIdx.x;
    const int lane = tid & 63;
    const int w = tid >> 6;
    const int fr = lane & 15;
    const int quad = lane >> 4;

    // stage Q strip: 16 rows x 192 shorts = 384 short8
    for (int i = tid; i < 384; i += 256) {
        int row = i / 24, p = i % 24;
        *(short8*)&Qs[row][p * 8] = *(const short8*)&Qc[(size_t)(h * TS + m0 + row) * KC + p * 8];
    }
    __syncthreads();
    bf16x8 af[6];
#pragma unroll
    for (int k = 0; k < 6; ++k) af[k] = *(const bf16x8*)&Qs[fr][k * 32 + quad * 8];

    floatx4 acc[32];
#pragma unroll
    for (int t = 0; t < 32; ++t) acc[t] = (floatx4){0.f, 0.f, 0.f, 0.f};

#pragma unroll
    for (int c = 0; c < 16; ++c) {
        // stage K chunk: 128 rows x 192 shorts = 1536 short8
#pragma unroll
        for (int l = 0; l < 6; ++l) {
            int idx = tid + l * 256;
            int row = idx / 12, p = idx % 12;
            *(short8*)((short*)&Ks[row][0] + p * 16) =
                *(const short8*)&Kc[(size_t)(h * TS + c * 128 + row) * KC + p * 16];
            *(short8*)((short*)&Ks[row][0] + p * 16 + 8) =
                *(const short8*)&Kc[(size_t)(h * TS + c * 128 + row) * KC + p * 16 + 8];
        }
        __syncthreads();
#pragma unroll
        for (int sub = 0; sub < 2; ++sub) {
            const int t = c * 2 + sub;
#pragma unroll
            for (int k = 0; k < 6; ++k) {
                bf16x8 bf = *(const bf16x8*)&Ks[w * 32 + sub * 16 + fr][k * 32 + quad * 8];
                acc[t] = __builtin_amdgcn_mfma_f32_16x16x32_bf16(af[k], bf, acc[t], 0, 0, 0);
            }
        }
        __syncthreads();
    }
    // mask add
#pragma unroll
    for (int t = 0; t < 32; ++t) {
        int col_g = (t >> 1) * 128 + w * 32 + (t & 1) * 16 + fr;
        float mb = (mask[col_g] - 1.0f) * 10000.0f;
#pragma unroll
        for (int r = 0; r < 4; ++r) acc[t][r] += mb;
    }
    // row max: in-lane over 32 tiles, then shfl over fr (lanes quad*16+fr), then LDS over waves
    float m4[4];
#pragma unroll
    for (int r = 0; r < 4; ++r) {
        float m = acc[0][r];
#pragma unroll
        for (int t = 1; t < 32; ++t) m = fmaxf(m, acc[t][r]);
#pragma unroll
        for (int off = 1; off <= 8; off <<= 1) m = fmaxf(m, __shfl_xor(m, off, 64));
        m4[r] = m;
    }
    if (fr == 0) {
#pragma unroll
        for (int r = 0; r < 4; ++r) smM[w][quad * 4 + r] = m4[r];
    }
    __syncthreads();
#pragma unroll
    for (int r = 0; r < 4; ++r)
        m4[r] = fmaxf(fmaxf(smM[0][quad * 4 + r], smM[1][quad * 4 + r]),
                      fmaxf(smM[2][quad * 4 + r], smM[3][quad * 4 + r]));
    // exp + sum
    float s4[4] = {0.f, 0.f, 0.f, 0.f};
#pragma unroll
    for (int t = 0; t < 32; ++t)
#pragma unroll
        for (int r = 0; r < 4; ++r) {
            float e = __expf(acc[t][r] - m4[r]);
            acc[t][r] = e;
            s4[r] += e;
        }
#pragma unroll
    for (int r = 0; r < 4; ++r)
#pragma unroll
        for (int off = 1; off <= 8; off <<= 1) s4[r] += __shfl_xor(s4[r], off, 64);
    if (fr == 0) {
#pragma unroll
        for (int r = 0; r < 4; ++r) smS[w][quad * 4 + r] = s4[r];
    }
    __syncthreads();
#pragma unroll
    for (int r = 0; r < 4; ++r) {
        float s = smS[0][quad * 4 + r] + smS[1][quad * 4 + r] +
                  smS[2][quad * 4 + r] + smS[3][quad * 4 + r];
        s4[r] = 1.0f / s;
    }
    // write softmaxed weights (fp32, the checked output)
#pragma unroll
    for (int t = 0; t < 32; ++t) {
        int col_g = (t >> 1) * 128 + w * 32 + (t & 1) * 16 + fr;
#pragma unroll
        for (int r = 0; r < 4; ++r)
            wout[(size_t)(h * TS + m0 + quad * 4 + r) * TS + col_g] = acc[t][r] * s4[r];
    }
}

// ---------------- context GEMM (bf16 MFMA): ctxb[s, h*64+d] = bf16(sum_t w[h,s,t] * v[h,t,d]) ----------------
__global__ __launch_bounds__(256) void k_ctx_mfma(
    const float* __restrict__ wout, const short* __restrict__ Vb, short* __restrict__ ctxb) {
    __shared__ __align__(16) short Asb[128][40];
    __shared__ __align__(16) short Bsb[64][40];
    const int h = blockIdx.y;
    const int m0 = blockIdx.x * 128;
    const int tid = threadIdx.x;
    const int lane = tid & 63;
    const int w = tid >> 6;
    const int wm = w * 32;             // wave's 32-row strip
    const int fr = lane & 15;
    const int quad = lane >> 4;
    floatx4 acc[2][4] = {};
    for (int k0 = 0; k0 < TS; k0 += 32) {
#pragma unroll
        for (int l = 0; l < 4; ++l) {
            int idx = tid + l * 256;
            int row = idx >> 3, col = (idx & 7) << 2;
            float4 a = *(const float4*)&wout[(size_t)(h * TS + m0 + row) * TS + k0 + col];
            s16x4 s;
            s[0] = f2bf(a.x); s[1] = f2bf(a.y); s[2] = f2bf(a.z); s[3] = f2bf(a.w);
            *(s16x4*)&Asb[row][col] = s;
        }
        {
            int row = tid >> 2, col = (tid & 3) << 3;
            *(short8*)&Bsb[row][col] =
                *(const short8*)&Vb[(size_t)(h * THD + row) * TS + k0 + col];
        }
        __syncthreads();
        bf16x8 af[2], bfr[4];
#pragma unroll
        for (int i = 0; i < 2; ++i) af[i] = *(const bf16x8*)&Asb[wm + i * 16 + fr][quad * 8];
#pragma unroll
        for (int j = 0; j < 4; ++j) bfr[j] = *(const bf16x8*)&Bsb[j * 16 + fr][quad * 8];
#pragma unroll
        for (int i = 0; i < 2; ++i)
#pragma unroll
            for (int j = 0; j < 4; ++j)
                acc[i][j] = __builtin_amdgcn_mfma_f32_16x16x32_bf16(af[i], bfr[j], acc[i][j], 0, 0, 0);
        __syncthreads();
    }
#pragma unroll
    for (int i = 0; i < 2; ++i)
#pragma unroll
        for (int j = 0; j < 4; ++j)
#pragma unroll
            for (int r = 0; r < 4; ++r) {
                int row_g = m0 + wm + i * 16 + quad * 4 + r;
                ctxb[(size_t)row_g * TH + h * THD + j * 16 + fr] = f2bf(acc[i][j][r]);
            }
}

extern "C" void kernel_launch(void* const* d_in, const int* in_sizes, int n_in,
                              void* d_out, int out_size, void* d_ws, size_t ws_size,
                              hipStream_t stream) {
    const float* hs    = (const float*)d_in[0];
    const float* mask  = (const float*)d_in[1];
    const float* Wq    = (const float*)d_in[2];
    const float* bq    = (const float*)d_in[3];
    const float* Wk    = (const float*)d_in[4];
    const float* bk    = (const float*)d_in[5];
    const float* Wv    = (const float*)d_in[6];
    const float* bv    = (const float*)d_in[7];
    const float* Wo    = (const float*)d_in[8];
    const float* bo    = (const float*)d_in[9];
    const float* omega = (const float*)d_in[10];
    const float* rffb  = (const float*)d_in[11];

    float* out0 = (float*)d_out;               // (S,H) final output
    float* wout = out0 + TS * TH;              // (NH,S,S) attention weights

    // workspace layout (floats); total ~44.2 MB
    float* ws   = (float*)d_ws;
    float* q    = ws;                          // NH*S*HD = 1572864 floats
    float* kbuf = ws + 1572864;
    short* Vb   = (short*)(ws + 3145728);      // NH*HD*TS shorts (transposed bf16 V)
    short* Wob  = (short*)(ws + 3932160);      // TH*TH shorts
    short* omegab = (short*)(ws + 4227072);    // NH*TNF*THD shorts
    float* invq = ws + 4718592;                // NH*S
    float* invk = ws + 4743168;
    short* ctxb = (short*)(ws + 4767744);      // S*H shorts
    short* Qc   = (short*)(ws + 6340608);      // NH*S*KC bf16
    short* Kc   = (short*)(ws + 8699904);

    // bf16 staging for the QKV projection, overlaid on wout (k_qk_sm overwrites wout later)
    short* Xb  = (short*)wout;                 // TS*TH shorts
    short* Wqb = Xb + (size_t)TS * TH;
    short* Wkb = Wqb + (size_t)TH * TH;
    short* Wvb = Wkb + (size_t)TH * TH;

    k_cvt_bf16<<<dim3(512, 6), 256, 0, stream>>>(hs, Wq, Wk, Wv, Wo, omega,
                                                 Xb, Wqb, Wkb, Wvb, Wob, omegab);
    k_proj_qkv_mfma<<<dim3(6, 16, 3), 256, 0, stream>>>(Xb, Wqb, Wkb, Wvb, bq, bk, bv,
                                                        q, kbuf, Vb, Qc, Kc);
    k_rownorm<<<dim3(TNH * TS, 2), 64, 0, stream>>>(q, kbuf, invq, invk);
    k_phi_mfma<<<dim3(16, 24), 256, 0, stream>>>(q, kbuf, invq, invk, omegab, rffb, Qc, Kc);
    k_phinorm<<<dim3(TNH * TS, 2), 128, 0, stream>>>(Qc, Kc);
    k_qk_sm<<<dim3(TS / 16, TNH), 256, 0, stream>>>(Qc, Kc, mask, wout);
    k_ctx_mfma<<<dim3(16, 12), 256, 0, stream>>>(wout, Vb, ctxb);
    k_proj_out_mfma<<<dim3(6, 16), 256, 0, stream>>>(ctxb, Wob, bo, out0);
}

// Round 6
// 489.040 us; speedup vs baseline: 1.1426x; 1.1426x over previous
//
#include <hip/hip_runtime.h>
#include <cmath>

#define TS 2048   // sequence
#define TH 768    // hidden
#define TNH 12    // heads
#define THD 64    // head dim
#define TNF 128   // rff features
#define KC 192    // concat K for scores (64 dot + 128 rff)

typedef __attribute__((ext_vector_type(4))) short s16x4;     // NOTE: 'short4' collides with HIP's vector types
typedef __attribute__((ext_vector_type(8))) short short8;
typedef __attribute__((ext_vector_type(8))) __bf16 bf16x8;   // matches builtin signature V8y
typedef __attribute__((ext_vector_type(4))) float floatx4;

// ---------------- fp32 <-> bf16 helpers ----------------
__device__ __forceinline__ short f2bf(float x) {
    union { float f; unsigned u; } v; v.f = x;
    unsigned r = v.u + 0x7FFFu + ((v.u >> 16) & 1u);   // round-nearest-even
    return (short)(r >> 16);
}
__device__ __forceinline__ float bf2f(short x) {
    union { unsigned u; float f; } v;
    v.u = ((unsigned)(unsigned short)x) << 16;
    return v.f;
}

// ---------------- wave helpers (wave = 64) ----------------
__device__ __forceinline__ float waveReduceSum(float v) {
#pragma unroll
    for (int off = 32; off >= 1; off >>= 1) v += __shfl_xor(v, off, 64);
    return v;
}
__device__ __forceinline__ float waveReduceMax(float v) {
#pragma unroll
    for (int off = 32; off >= 1; off >>= 1) v = fmaxf(v, __shfl_xor(v, off, 64));
    return v;
}

// ---------------- cvt: fp32 -> bf16 for hs, Wq, Wk, Wv, Wo, omega ----------------
__global__ __launch_bounds__(256) void k_cvt_bf16(
    const float* __restrict__ s0, const float* __restrict__ s1,
    const float* __restrict__ s2, const float* __restrict__ s3,
    const float* __restrict__ s4, const float* __restrict__ s5,
    short* __restrict__ d0, short* __restrict__ d1,
    short* __restrict__ d2, short* __restrict__ d3,
    short* __restrict__ d4, short* __restrict__ d5) {
    const int y = blockIdx.y;
    const float* srcs[6] = {s0, s1, s2, s3, s4, s5};
    short* dsts[6] = {d0, d1, d2, d3, d4, d5};
    const int n4s[6] = {TS * TH / 4, TH * TH / 4, TH * TH / 4, TH * TH / 4,
                        TH * TH / 4, TNH * TNF * THD / 4};
    const float* src = srcs[y];
    short* dst = dsts[y];
    const int n4 = n4s[y];
    for (int i = blockIdx.x * 256 + threadIdx.x; i < n4; i += gridDim.x * 256) {
        float4 v = ((const float4*)src)[i];
        s16x4 o;
        o[0] = f2bf(v.x); o[1] = f2bf(v.y); o[2] = f2bf(v.z); o[3] = f2bf(v.w);
        *(s16x4*)&dst[i * 4] = o;
    }
}

// ---------------- QKV projection (bf16 MFMA) + fused row-norm ----------------
// z==0 (q): Qc[row][0:64] = bf16(0.1125*q); invq[row] = 1/(0.1125*(||q||+1e-5))
//           (so phi's  bf16(0.1125 q) * invq  ==  q/(||q||+1e-5), the reference qn)
// z==1 (k): Kc[row][0:64] = bf16(k);        invk[row] = 1/(||k||+1e-5)
// z==2 (v): Vb[h][d][t] = bf16(v)  (transposed for the PV MFMA B-operand)
// No fp32 q/k buffers anymore. A wave's 64 n-cols = one head's full d-extent, so the
// row sum-of-squares is in-thread (j,r) + shfl over fr (quad-group stays intact).
__global__ __launch_bounds__(256) void k_proj_qkv_mfma(
    const short* __restrict__ Xb,
    const short* __restrict__ Wqb, const short* __restrict__ Wkb, const short* __restrict__ Wvb,
    const float* __restrict__ b0, const float* __restrict__ b1, const float* __restrict__ b2,
    float* __restrict__ invq, float* __restrict__ invk, short* __restrict__ Vb,
    short* __restrict__ Qc, short* __restrict__ Kc) {
    __shared__ __align__(16) short Asb[128][40];
    __shared__ __align__(16) short Bsb[128][40];
    const int z = blockIdx.z;
    const short* W = (z == 0) ? Wqb : ((z == 1) ? Wkb : Wvb);
    const float* bias = (z == 0) ? b0 : ((z == 1) ? b1 : b2);
    const int n0 = blockIdx.x * 128;
    const int m0 = blockIdx.y * 128;
    const int tid = threadIdx.x;
    const int lane = tid & 63;
    const int w = tid >> 6;
    const int wm = (w >> 1) * 64, wn = (w & 1) * 64;
    const int fr = lane & 15;
    const int quad = lane >> 4;

    floatx4 acc[4][4] = {};

    for (int k0 = 0; k0 < TH; k0 += 32) {
#pragma unroll
        for (int l = 0; l < 2; ++l) {
            int c = tid + l * 256;
            int row = c >> 2, col = (c & 3) << 3;
            *(short8*)&Asb[row][col] = *(const short8*)&Xb[(size_t)(m0 + row) * TH + k0 + col];
            *(short8*)&Bsb[row][col] = *(const short8*)&W[(size_t)(n0 + row) * TH + k0 + col];
        }
        __syncthreads();
        bf16x8 af[4], bfr[4];
#pragma unroll
        for (int i = 0; i < 4; ++i) af[i] = *(const bf16x8*)&Asb[wm + i * 16 + fr][quad * 8];
#pragma unroll
        for (int j = 0; j < 4; ++j) bfr[j] = *(const bf16x8*)&Bsb[wn + j * 16 + fr][quad * 8];
#pragma unroll
        for (int i = 0; i < 4; ++i)
#pragma unroll
            for (int j = 0; j < 4; ++j)
                acc[i][j] = __builtin_amdgcn_mfma_f32_16x16x32_bf16(af[i], bfr[j], acc[i][j], 0, 0, 0);
        __syncthreads();
    }
    // epilogue: C/D layout col=lane&15, row=(lane>>4)*4+reg
    if (z == 2) {
#pragma unroll
        for (int j = 0; j < 4; ++j) {
            int n = n0 + wn + j * 16 + fr;
            int h = n >> 6, d = n & 63;
            float bv = bias[n];
#pragma unroll
            for (int i = 0; i < 4; ++i) {
                int t = m0 + wm + i * 16 + quad * 4;
                s16x4 pk;
#pragma unroll
                for (int r = 0; r < 4; ++r) pk[r] = f2bf(acc[i][j][r] + bv);
                *(s16x4*)&Vb[(size_t)(h * THD + d) * TS + t] = pk;
            }
        }
    } else {
        short* cc = z ? Kc : Qc;
        float* invd = z ? invk : invq;
        const float qs = z ? 1.0f : 0.1125f;
        const int hh = (n0 + wn) >> 6;        // one head per wave
        float ssr[4][4] = {};
#pragma unroll
        for (int j = 0; j < 4; ++j) {
            int n = n0 + wn + j * 16 + fr;
            int d = n & 63;
            float bv = bias[n];
#pragma unroll
            for (int i = 0; i < 4; ++i) {
#pragma unroll
                for (int r = 0; r < 4; ++r) {
                    int m = m0 + wm + i * 16 + quad * 4 + r;
                    float val = acc[i][j][r] + bv;
                    cc[(size_t)(hh * TS + m) * KC + d] = f2bf(val * qs);
                    ssr[i][r] += val * val;
                }
            }
        }
#pragma unroll
        for (int i = 0; i < 4; ++i)
#pragma unroll
            for (int r = 0; r < 4; ++r) {
                float ss = ssr[i][r];
#pragma unroll
                for (int off = 1; off <= 8; off <<= 1) ss += __shfl_xor(ss, off, 64);
                if (fr == 0) {
                    int m = m0 + wm + i * 16 + quad * 4 + r;
                    invd[hh * TS + m] = 1.0f / (qs * (sqrtf(ss) + 1e-5f));
                }
            }
    }
}

// ---------------- output projection (bf16 MFMA): out = ctxb @ Wob^T + bo ----------------
__global__ __launch_bounds__(256) void k_proj_out_mfma(
    const short* __restrict__ ctxb, const short* __restrict__ Wob,
    const float* __restrict__ bias, float* __restrict__ out) {
    __shared__ __align__(16) short Asb[128][40];
    __shared__ __align__(16) short Bsb[128][40];
    const int n0 = blockIdx.x * 128;
    const int m0 = blockIdx.y * 128;
    const int tid = threadIdx.x;
    const int lane = tid & 63;
    const int w = tid >> 6;
    const int wm = (w >> 1) * 64, wn = (w & 1) * 64;
    const int fr = lane & 15;
    const int quad = lane >> 4;

    floatx4 acc[4][4] = {};

    for (int k0 = 0; k0 < TH; k0 += 32) {
#pragma unroll
        for (int l = 0; l < 2; ++l) {
            int c = tid + l * 256;
            int row = c >> 2, col = (c & 3) << 3;
            *(short8*)&Asb[row][col] = *(const short8*)&ctxb[(size_t)(m0 + row) * TH + k0 + col];
            *(short8*)&Bsb[row][col] = *(const short8*)&Wob[(size_t)(n0 + row) * TH + k0 + col];
        }
        __syncthreads();
        bf16x8 af[4], bfr[4];
#pragma unroll
        for (int i = 0; i < 4; ++i) af[i] = *(const bf16x8*)&Asb[wm + i * 16 + fr][quad * 8];
#pragma unroll
        for (int j = 0; j < 4; ++j) bfr[j] = *(const bf16x8*)&Bsb[wn + j * 16 + fr][quad * 8];
#pragma unroll
        for (int i = 0; i < 4; ++i)
#pragma unroll
            for (int j = 0; j < 4; ++j)
                acc[i][j] = __builtin_amdgcn_mfma_f32_16x16x32_bf16(af[i], bfr[j], acc[i][j], 0, 0, 0);
        __syncthreads();
    }
#pragma unroll
    for (int j = 0; j < 4; ++j) {
        int n = n0 + wn + j * 16 + fr;
        float bv = bias[n];
#pragma unroll
        for (int i = 0; i < 4; ++i)
#pragma unroll
            for (int r = 0; r < 4; ++r) {
                int m = m0 + wm + i * 16 + quad * 4 + r;
                out[(size_t)m * TH + n] = acc[i][j][r] + bv;
            }
    }
}

// ---------------- phi (bf16 MFMA) + fused row-L2-normalize ----------------
// A = bf16 q/k from Qc/Kc cols [0:64], scaled by inv during staging (-> normalized input).
// B = bf16 omega. Epilogue: p = 0.125*cos(z+b) in fp32 regs, row-norm over all 128 f
// (in-thread j + shfl fr + 1KB LDS wave-pair exchange), write bf16(p*scale) once.
// Folds (1-alpha)=0.1 into the q side. Kills k_phinorm and its 19MB round trip.
__global__ __launch_bounds__(256) void k_phi_mfma(
    const float* __restrict__ invq, const float* __restrict__ invk,
    const short* __restrict__ omegab, const float* __restrict__ rffb,
    short* __restrict__ Qc, short* __restrict__ Kc) {
    __shared__ __align__(16) short Asb[128][40];
    __shared__ __align__(16) short Bsb[128][40];
    __shared__ float smP[4][64];
    const int z = blockIdx.y;
    const int h = z >> 1, which = z & 1;
    const float* inv = which ? invk : invq;
    short* buf = which ? Kc : Qc;      // read cols [0:64], write cols [64:192]
    const int m0 = blockIdx.x * 128;
    const int tid = threadIdx.x;
    const int lane = tid & 63;
    const int w = tid >> 6;
    const int wm = (w >> 1) * 64, wn = (w & 1) * 64;
    const int fr = lane & 15;
    const int quad = lane >> 4;

    floatx4 acc[4][4] = {};

    for (int k0 = 0; k0 < THD; k0 += 32) {
#pragma unroll
        for (int l = 0; l < 2; ++l) {
            int c = tid + l * 256;
            int row = c >> 2, col = (c & 3) << 3;
            int rq = h * TS + m0 + row;
            float s = inv[rq];
            short8 a = *(const short8*)&buf[(size_t)rq * KC + k0 + col];
            short8 o;
#pragma unroll
            for (int e = 0; e < 8; ++e) o[e] = f2bf(bf2f(a[e]) * s);
            *(short8*)&Asb[row][col] = o;
            *(short8*)&Bsb[row][col] = *(const short8*)&omegab[(size_t)(h * TNF + row) * THD + k0 + col];
        }
        __syncthreads();
        bf16x8 af[4], bfr[4];
#pragma unroll
        for (int i = 0; i < 4; ++i) af[i] = *(const bf16x8*)&Asb[wm + i * 16 + fr][quad * 8];
#pragma unroll
        for (int j = 0; j < 4; ++j) bfr[j] = *(const bf16x8*)&Bsb[wn + j * 16 + fr][quad * 8];
#pragma unroll
        for (int i = 0; i < 4; ++i)
#pragma unroll
            for (int j = 0; j < 4; ++j)
                acc[i][j] = __builtin_amdgcn_mfma_f32_16x16x32_bf16(af[i], bfr[j], acc[i][j], 0, 0, 0);
        __syncthreads();
    }
    // epilogue: p = 0.125*cos(acc + b) in place; ss over this wave's 64 f, then wave-pair sum
    float bvj[4];
#pragma unroll
    for (int j = 0; j < 4; ++j) bvj[j] = rffb[h * TNF + wn + j * 16 + fr];
    float ssr[4][4] = {};
#pragma unroll
    for (int i = 0; i < 4; ++i)
#pragma unroll
        for (int j = 0; j < 4; ++j)
#pragma unroll
            for (int r = 0; r < 4; ++r) {
                float p = 0.125f * cosf(acc[i][j][r] + bvj[j]);   // SIGMA = 1
                acc[i][j][r] = p;
                ssr[i][r] += p * p;
            }
#pragma unroll
    for (int i = 0; i < 4; ++i)
#pragma unroll
        for (int r = 0; r < 4; ++r) {
#pragma unroll
            for (int off = 1; off <= 8; off <<= 1) ssr[i][r] += __shfl_xor(ssr[i][r], off, 64);
        }
    if (fr == 0) {
#pragma unroll
        for (int i = 0; i < 4; ++i)
#pragma unroll
            for (int r = 0; r < 4; ++r) smP[w][i * 16 + quad * 4 + r] = ssr[i][r];
    }
    __syncthreads();
    const float scale0 = which ? 1.0f : 0.1f;
#pragma unroll
    for (int i = 0; i < 4; ++i)
#pragma unroll
        for (int r = 0; r < 4; ++r) {
            int rl = i * 16 + quad * 4 + r;
            float ss = smP[w][rl] + smP[w ^ 1][rl];
            float sc = scale0 / (sqrtf(ss) + 1e-6f);
            int m = m0 + wm + rl;
#pragma unroll
            for (int j = 0; j < 4; ++j) {
                int f = wn + j * 16 + fr;
                buf[(size_t)(h * TS + m) * KC + 64 + f] = f2bf(acc[i][j][r] * sc);
            }
        }
}

// ---------------- scores: bf16 MFMA concat-K GEMM (K = 192), 128x128 tile, 4 waves ----------------
__global__ __launch_bounds__(256) void k_scores_mfma(
    const short* __restrict__ Qc, const short* __restrict__ Kc,
    const float* __restrict__ mask, float* __restrict__ wout) {
    __shared__ __align__(16) short Asb[128][40];   // 80 B row stride: 16B-aligned, <=2-way bank alias
    __shared__ __align__(16) short Bsb[128][40];
    const int h = blockIdx.z;
    const int n0 = blockIdx.x * 128;
    const int m0 = blockIdx.y * 128;
    const int tid = threadIdx.x;
    const int lane = tid & 63;
    const int w = tid >> 6;
    const int wm = (w >> 1) * 64, wn = (w & 1) * 64;
    const int fr = lane & 15;          // fragment row/col within 16
    const int quad = lane >> 4;        // k-quad

    floatx4 acc[4][4] = {};

    for (int k0 = 0; k0 < KC; k0 += 32) {
#pragma unroll
        for (int l = 0; l < 2; ++l) {
            int c = tid + l * 256;
            int row = c >> 2, col = (c & 3) << 3;
            short8 a = *(const short8*)&Qc[(size_t)(h * TS + m0 + row) * KC + k0 + col];
            *(short8*)&Asb[row][col] = a;
            short8 b = *(const short8*)&Kc[(size_t)(h * TS + n0 + row) * KC + k0 + col];
            *(short8*)&Bsb[row][col] = b;
        }
        __syncthreads();
        bf16x8 af[4], bfr[4];
#pragma unroll
        for (int i = 0; i < 4; ++i) af[i] = *(const bf16x8*)&Asb[wm + i * 16 + fr][quad * 8];
#pragma unroll
        for (int j = 0; j < 4; ++j) bfr[j] = *(const bf16x8*)&Bsb[wn + j * 16 + fr][quad * 8];
#pragma unroll
        for (int i = 0; i < 4; ++i)
#pragma unroll
            for (int j = 0; j < 4; ++j)
                acc[i][j] = __builtin_amdgcn_mfma_f32_16x16x32_bf16(af[i], bfr[j], acc[i][j], 0, 0, 0);
        __syncthreads();
    }
    // epilogue: C/D layout col=lane&15, row=(lane>>4)*4+reg
#pragma unroll
    for (int j = 0; j < 4; ++j) {
        int col_g = n0 + wn + j * 16 + fr;
        float mb = (mask[col_g] - 1.0f) * 10000.0f;
#pragma unroll
        for (int i = 0; i < 4; ++i) {
#pragma unroll
            for (int r = 0; r < 4; ++r) {
                int row_g = m0 + wm + i * 16 + quad * 4 + r;
                wout[(size_t)(h * TS + row_g) * TS + col_g] = acc[i][j][r] + mb;
            }
        }
    }
}

// ---------------- softmax over rows of 2048, in place ----------------
__global__ __launch_bounds__(256) void k_softmax(float* __restrict__ wout) {
    const int row = blockIdx.x;
    float4* p = (float4*)(wout + (size_t)row * TS);
    const int tid = threadIdx.x;
    float4 x0 = p[tid], x1 = p[tid + 256];
    float mx = fmaxf(fmaxf(fmaxf(x0.x, x0.y), fmaxf(x0.z, x0.w)),
                     fmaxf(fmaxf(x1.x, x1.y), fmaxf(x1.z, x1.w)));
    mx = waveReduceMax(mx);
    __shared__ float rm[4];
    __shared__ float rs[4];
    if ((tid & 63) == 0) rm[tid >> 6] = mx;
    __syncthreads();
    mx = fmaxf(fmaxf(rm[0], rm[1]), fmaxf(rm[2], rm[3]));
    float e[8];
    e[0] = __expf(x0.x - mx); e[1] = __expf(x0.y - mx);
    e[2] = __expf(x0.z - mx); e[3] = __expf(x0.w - mx);
    e[4] = __expf(x1.x - mx); e[5] = __expf(x1.y - mx);
    e[6] = __expf(x1.z - mx); e[7] = __expf(x1.w - mx);
    float sum = ((e[0] + e[1]) + (e[2] + e[3])) + ((e[4] + e[5]) + (e[6] + e[7]));
    sum = waveReduceSum(sum);
    if ((tid & 63) == 0) rs[tid >> 6] = sum;
    __syncthreads();
    sum = rs[0] + rs[1] + rs[2] + rs[3];
    float rinv = 1.0f / sum;
    x0.x = e[0] * rinv; x0.y = e[1] * rinv; x0.z = e[2] * rinv; x0.w = e[3] * rinv;
    x1.x = e[4] * rinv; x1.y = e[5] * rinv; x1.z = e[6] * rinv; x1.w = e[7] * rinv;
    p[tid] = x0;
    p[tid + 256] = x1;
}

// ---------------- context GEMM (bf16 MFMA): ctxb[s, h*64+d] = bf16(sum_t w[h,s,t] * v[h,t,d]) ----------------
__global__ __launch_bounds__(256) void k_ctx_mfma(
    const float* __restrict__ wout, const short* __restrict__ Vb, short* __restrict__ ctxb) {
    __shared__ __align__(16) short Asb[128][40];
    __shared__ __align__(16) short Bsb[64][40];
    const int h = blockIdx.y;
    const int m0 = blockIdx.x * 128;
    const int tid = threadIdx.x;
    const int lane = tid & 63;
    const int w = tid >> 6;
    const int wm = w * 32;             // wave's 32-row strip
    const int fr = lane & 15;
    const int quad = lane >> 4;
    floatx4 acc[2][4] = {};
    for (int k0 = 0; k0 < TS; k0 += 32) {
#pragma unroll
        for (int l = 0; l < 4; ++l) {
            int idx = tid + l * 256;
            int row = idx >> 3, col = (idx & 7) << 2;
            float4 a = *(const float4*)&wout[(size_t)(h * TS + m0 + row) * TS + k0 + col];
            s16x4 s;
            s[0] = f2bf(a.x); s[1] = f2bf(a.y); s[2] = f2bf(a.z); s[3] = f2bf(a.w);
            *(s16x4*)&Asb[row][col] = s;
        }
        {
            int row = tid >> 2, col = (tid & 3) << 3;
            *(short8*)&Bsb[row][col] =
                *(const short8*)&Vb[(size_t)(h * THD + row) * TS + k0 + col];
        }
        __syncthreads();
        bf16x8 af[2], bfr[4];
#pragma unroll
        for (int i = 0; i < 2; ++i) af[i] = *(const bf16x8*)&Asb[wm + i * 16 + fr][quad * 8];
#pragma unroll
        for (int j = 0; j < 4; ++j) bfr[j] = *(const bf16x8*)&Bsb[j * 16 + fr][quad * 8];
#pragma unroll
        for (int i = 0; i < 2; ++i)
#pragma unroll
            for (int j = 0; j < 4; ++j)
                acc[i][j] = __builtin_amdgcn_mfma_f32_16x16x32_bf16(af[i], bfr[j], acc[i][j], 0, 0, 0);
        __syncthreads();
    }
#pragma unroll
    for (int i = 0; i < 2; ++i)
#pragma unroll
        for (int j = 0; j < 4; ++j)
#pragma unroll
            for (int r = 0; r < 4; ++r) {
                int row_g = m0 + wm + i * 16 + quad * 4 + r;
                ctxb[(size_t)row_g * TH + h * THD + j * 16 + fr] = f2bf(acc[i][j][r]);
            }
}

extern "C" void kernel_launch(void* const* d_in, const int* in_sizes, int n_in,
                              void* d_out, int out_size, void* d_ws, size_t ws_size,
                              hipStream_t stream) {
    const float* hs    = (const float*)d_in[0];
    const float* mask  = (const float*)d_in[1];
    const float* Wq    = (const float*)d_in[2];
    const float* bq    = (const float*)d_in[3];
    const float* Wk    = (const float*)d_in[4];
    const float* bk    = (const float*)d_in[5];
    const float* Wv    = (const float*)d_in[6];
    const float* bv    = (const float*)d_in[7];
    const float* Wo    = (const float*)d_in[8];
    const float* bo    = (const float*)d_in[9];
    const float* omega = (const float*)d_in[10];
    const float* rffb  = (const float*)d_in[11];

    float* out0 = (float*)d_out;               // (S,H) final output
    float* wout = out0 + TS * TH;              // (NH,S,S) attention weights

    // workspace layout (floats); total ~44.2 MB (fp32 q/k slots now unused)
    float* ws   = (float*)d_ws;
    short* Vb   = (short*)(ws + 3145728);      // NH*HD*TS shorts (transposed bf16 V)
    short* Wob  = (short*)(ws + 3932160);      // TH*TH shorts
    short* omegab = (short*)(ws + 4227072);    // NH*TNF*THD shorts
    float* invq = ws + 4718592;                // NH*S
    float* invk = ws + 4743168;
    short* ctxb = (short*)(ws + 4767744);      // S*H shorts
    short* Qc   = (short*)(ws + 6340608);      // NH*S*KC bf16
    short* Kc   = (short*)(ws + 8699904);

    // bf16 staging for the QKV projection, overlaid on wout (k_scores overwrites wout later)
    short* Xb  = (short*)wout;                 // TS*TH shorts
    short* Wqb = Xb + (size_t)TS * TH;
    short* Wkb = Wqb + (size_t)TH * TH;
    short* Wvb = Wkb + (size_t)TH * TH;

    k_cvt_bf16<<<dim3(512, 6), 256, 0, stream>>>(hs, Wq, Wk, Wv, Wo, omega,
                                                 Xb, Wqb, Wkb, Wvb, Wob, omegab);
    k_proj_qkv_mfma<<<dim3(6, 16, 3), 256, 0, stream>>>(Xb, Wqb, Wkb, Wvb, bq, bk, bv,
                                                        invq, invk, Vb, Qc, Kc);
    k_phi_mfma<<<dim3(16, 24), 256, 0, stream>>>(invq, invk, omegab, rffb, Qc, Kc);
    k_scores_mfma<<<dim3(16, 16, 12), 256, 0, stream>>>(Qc, Kc, mask, wout);
    k_softmax<<<TNH * TS, 256, 0, stream>>>(wout);
    k_ctx_mfma<<<dim3(16, 12), 256, 0, stream>>>(wout, Vb, ctxb);
    k_proj_out_mfma<<<dim3(6, 16), 256, 0, stream>>>(ctxb, Wob, bo, out0);
}